// Round 4
// baseline (8042.567 us; speedup 1.0000x reference)
//
#include <hip/hip_runtime.h>

#define Bn 32
#define Tn 512
#define Cn 8
#define Hn 256
#define Gn 1024           // 4*Hn
#define NTHR 256          // 4 waves: 2 row-groups x 2 batch-groups
#define SLC  32           // slices per channel (each owns 8 h-indices)
#define NBLK (Cn*SLC)     // 256 workgroups
#define CBHE (Cn*Bn*Hn)   // 65536 elements (one h snapshot, all channels)
#define HB2  (2*CBHE)     // double-buffered h array, in ushorts
#define GP   36           // gate-buffer pitch (floats): 2-way banks on write & read

typedef __attribute__((ext_vector_type(8))) __bf16 bf16x8;
typedef __attribute__((ext_vector_type(8))) short  short8;
typedef __attribute__((ext_vector_type(4))) float  f32x4;

__device__ __forceinline__ unsigned bfr(float f) {            // fp32 -> bf16 bits, RNE
    unsigned u = __float_as_uint(f);
    return (u + 0x7fffu + ((u >> 16) & 1u)) >> 16;
}
__device__ __forceinline__ float sigmf(float v)  { return 1.0f / (1.0f + __expf(-v)); }
__device__ __forceinline__ float tanh_f(float v) { return 1.0f - 2.0f / (__expf(2.0f * v) + 1.0f); }

__device__ __forceinline__ f32x4 mf(short8 a, short8 b, f32x4 c) {
    return __builtin_amdgcn_mfma_f32_16x16x32_bf16(
        __builtin_bit_cast(bf16x8, a), __builtin_bit_cast(bf16x8, b), c, 0, 0, 0);
}

// split 8 consecutive fp32 into bf16 hi + bf16 lo fragments
__device__ __forceinline__ void splitw(const float* __restrict__ p, short8& hi, short8& lo) {
    short8 h, l;
#pragma unroll
    for (int j = 0; j < 8; ++j) {
        const float v = p[j];
        const unsigned hb = bfr(v);
        const float hf = __uint_as_float(hb << 16);
        h[j] = (short)hb;
        l[j] = (short)bfr(v - hf);
    }
    hi = h; lo = l;
}

__global__ void __launch_bounds__(NTHR, 1)
lstm_mfma(const float* __restrict__ x,
          const float* __restrict__ Wih1, const float* __restrict__ Whh1,
          const float* __restrict__ bih1, const float* __restrict__ bhh1,
          const float* __restrict__ Wih2, const float* __restrict__ Whh2,
          const float* __restrict__ bih2, const float* __restrict__ bhh2,
          const float* __restrict__ Wlin, const float* __restrict__ blin,
          float* __restrict__ out, void* __restrict__ wsv, int use_part) {
    __shared__ float g1buf[32 * GP];   // layer-1 gate exchange (32 rows x 32 batches, padded)
    __shared__ float g2buf[32 * GP];   // layer-2 gate exchange

    unsigned short* H1h = (unsigned short*)wsv;  // [2][C][B][H] bf16-hi of h1
    unsigned short* H1l = H1h + HB2;
    unsigned short* H2h = H1l + HB2;
    unsigned short* H2l = H2h + HB2;
    unsigned* flags = (unsigned*)(H2l + HB2);       // [C][SLC] monotone flags, 256B apart
    float* part = (float*)(flags + Cn * SLC * 64);  // [T][C][SLC][B] out partials

    const int tid  = threadIdx.x;
    const int wg   = blockIdx.x;
    const int c    = wg & 7;            // channel (XCD-local under round-robin dispatch)
    const int s    = wg >> 3;           // slice: h-indices s*8 .. s*8+7
    const int lane = tid & 63;
    const int wid  = tid >> 6;          // 0..3
    const int n    = lane & 15;
    const int quad = lane >> 4;
    const int rbase = (wid & 1) * 16;   // wave's gate-row half (rows 0..31)
    const int bbase = (wid >> 1) * 16;  // wave's batch half

    // ---- permanent A-fragments: all three weight matrices, bf16 hi+lo, in VGPRs ----
    const int mrow = rbase + n;                                      // wg row (0..31)
    const size_t gm = (size_t)((mrow >> 3) * Hn + s * 8 + (mrow & 7)); // global gate row
    short8 w1h[8], w1l[8], w2h[8], w2l[8], w3h[8], w3l[8];
    {
        const size_t wbase = (size_t)c * Gn * Hn + gm * Hn + quad * 8;
        const float* p1 = Whh1 + wbase;
        const float* p2 = Wih2 + wbase;
        const float* p3 = Whh2 + wbase;
#pragma unroll
        for (int kk = 0; kk < 8; ++kk) {
            splitw(p1 + kk * 32, w1h[kk], w1l[kk]);
            splitw(p2 + kk * 32, w2h[kk], w2l[kk]);
            splitw(p3 + kk * 32, w3h[kk], w3l[kk]);
        }
    }

    // per-lane epilogue constants for the 4 accumulator rows (row = rbase + quad*4 + reg)
    float wi1_r[4], bs1_r[4], bs2_r[4];
#pragma unroll
    for (int reg = 0; reg < 4; ++reg) {
        const int r = rbase + quad * 4 + reg;
        const int g = (r >> 3) * Hn + s * 8 + (r & 7);
        wi1_r[reg] = Wih1[c * Gn + g];
        bs1_r[reg] = bih1[c * Gn + g] + bhh1[c * Gn + g];
        bs2_r[reg] = bih2[c * Gn + g] + bhh2[c * Gn + g];
    }

    // cell-update mapping: thread -> (jj = tid&7 h-idx within slice, bb = tid>>3 batch)
    const int jj = tid & 7;
    const int bb = tid >> 3;
    const float wl = Wlin[c * Hn + s * 8 + jj];
    const float bl = blin[c];

    float c1 = 0.0f, c2 = 0.0f;

    for (int t = 0; t <= Tn; ++t) {
        const bool doA = (t < Tn);      // layer-1 step t
        const bool doB = (t >= 1);      // layer-2 step t-1 (pipelined one behind)
        const int rd1 = (t + 1) & 1, wr1 = t & 1;        // h1 buffers
        const int rd2 = t & 1,       wr2 = (t + 1) & 1;  // h2 buffers

        const float xv = doA ? x[((bbase + n) * Tn + t) * Cn + c] : 0.0f;  // prefetch early

        // ---- B-fragments of h2[t-2] ----
        const int hoff2 = ((rd2 * Cn + c) * Bn + (bbase + n)) * Hn + quad * 8;
        short8 f2h[8], f2l[8];
#pragma unroll
        for (int kk = 0; kk < 8; ++kk) {
            f2h[kk] = *(const short8*)(H2h + hoff2 + kk * 32);
            f2l[kk] = *(const short8*)(H2l + hoff2 + kk * 32);
        }
        f32x4 a2a = {0,0,0,0}, a2x = {0,0,0,0};
#pragma unroll
        for (int kk = 0; kk < 8; ++kk) {            // Whh2 . h2[t-2]
            a2a = mf(w3h[kk], f2h[kk], a2a);
            a2x = mf(w3l[kk], f2h[kk], mf(w3h[kk], f2l[kk], a2x));
        }

        // ---- B-fragments of h1[t-1] ----
        const int hoff1 = ((rd1 * Cn + c) * Bn + (bbase + n)) * Hn + quad * 8;
        short8 f1h[8], f1l[8];
#pragma unroll
        for (int kk = 0; kk < 8; ++kk) {
            f1h[kk] = *(const short8*)(H1h + hoff1 + kk * 32);
            f1l[kk] = *(const short8*)(H1l + hoff1 + kk * 32);
        }
        f32x4 a1a = {0,0,0,0}, a1x = {0,0,0,0};
#pragma unroll
        for (int kk = 0; kk < 8; ++kk) {            // Whh1 . h1[t-1]  and  Wih2 . h1[t-1]
            a1a = mf(w1h[kk], f1h[kk], a1a);
            a1x = mf(w1l[kk], f1h[kk], mf(w1h[kk], f1l[kk], a1x));
            a2a = mf(w2h[kk], f1h[kk], a2a);
            a2x = mf(w2l[kk], f1h[kk], mf(w2h[kk], f1l[kk], a2x));
        }

        // ---- write gates to LDS (C/D layout: col = lane&15, row = quad*4+reg) ----
#pragma unroll
        for (int reg = 0; reg < 4; ++reg) {
            const int r = rbase + quad * 4 + reg;
            g1buf[r * GP + bbase + n] = a1a[reg] + a1x[reg] + xv * wi1_r[reg] + bs1_r[reg];
            g2buf[r * GP + bbase + n] = a2a[reg] + a2x[reg] + bs2_r[reg];
        }
        __syncthreads();

        // ---- layer-1 cell update, publish h1[t] as split bf16 ----
        if (doA) {
            const float iv = sigmf(g1buf[jj * GP + bb]);
            const float fv = sigmf(g1buf[(8 + jj) * GP + bb]);
            const float gv = tanh_f(g1buf[(16 + jj) * GP + bb]);
            const float ov = sigmf(g1buf[(24 + jj) * GP + bb]);
            c1 = fv * c1 + iv * gv;
            const float h1v = ov * tanh_f(c1);
            const unsigned hb = bfr(h1v);
            const float hf = __uint_as_float(hb << 16);
            const unsigned lb = bfr(h1v - hf);
            const int idx = ((wr1 * Cn + c) * Bn + bb) * Hn + s * 8 + jj;
            H1h[idx] = (unsigned short)hb;
            H1l[idx] = (unsigned short)lb;
        }
        // ---- layer-2 cell update, publish h2[t-1], out partial ----
        if (doB) {
            const float iv = sigmf(g2buf[jj * GP + bb]);
            const float fv = sigmf(g2buf[(8 + jj) * GP + bb]);
            const float gv = tanh_f(g2buf[(16 + jj) * GP + bb]);
            const float ov = sigmf(g2buf[(24 + jj) * GP + bb]);
            c2 = fv * c2 + iv * gv;
            const float h2v = ov * tanh_f(c2);
            const unsigned hb = bfr(h2v);
            const float hf = __uint_as_float(hb << 16);
            const unsigned lb = bfr(h2v - hf);
            const int idx = ((wr2 * Cn + c) * Bn + bb) * Hn + s * 8 + jj;
            H2h[idx] = (unsigned short)hb;
            H2l[idx] = (unsigned short)lb;

            float pv = h2v * wl;                      // partial of out over this slice's 8 h
            pv += __shfl_xor(pv, 1, 64);
            pv += __shfl_xor(pv, 2, 64);
            pv += __shfl_xor(pv, 4, 64);
            if (jj == 0) {
                if (use_part) {
                    part[(((t - 1) * Cn + c) * SLC + s) * Bn + bb] = pv;
                } else {
                    atomicAdd(&out[(bb * Tn + (t - 1)) * Cn + c], pv + (s == 0 ? bl : 0.0f));
                }
            }
        }

        // ---- flag barrier: release own flag, wave0 polls all 32 in parallel ----
        __syncthreads();                 // drains vmcnt: all wg h stores in L2
        if (tid == 0) {
            __threadfence();             // release: push to coherence point
            __hip_atomic_store(&flags[(c * SLC + s) * 64], (unsigned)(t + 1),
                               __ATOMIC_RELAXED, __HIP_MEMORY_SCOPE_AGENT);
        }
        if (tid < 64) {
            const unsigned tgt = (unsigned)(t + 1);
            bool mine;
            do {
                mine = (tid < SLC)
                     ? (__hip_atomic_load(&flags[(c * SLC + tid) * 64],
                                          __ATOMIC_RELAXED, __HIP_MEMORY_SCOPE_AGENT) >= tgt)
                     : true;
            } while (!__all(mine));
        }
        if (tid == 0) __threadfence();   // acquire: invalidate stale lines before next h reads
        __syncthreads();
    }
}

__global__ void reduce_out(const float* __restrict__ part, const float* __restrict__ blin,
                           float* __restrict__ out) {
    const int t = blockIdx.x;           // 512
    const int c = threadIdx.x >> 5;     // 8
    const int b = threadIdx.x & 31;     // 32
    float v = blin[c];
#pragma unroll
    for (int s = 0; s < SLC; ++s) v += part[((t * Cn + c) * SLC + s) * Bn + b];
    out[(b * Tn + t) * Cn + c] = v;
}

extern "C" void kernel_launch(void* const* d_in, const int* in_sizes, int n_in,
                              void* d_out, int out_size, void* d_ws, size_t ws_size,
                              hipStream_t stream) {
    const float* x    = (const float*)d_in[0];
    const float* Wih1 = (const float*)d_in[1];
    const float* Whh1 = (const float*)d_in[2];
    const float* bih1 = (const float*)d_in[3];
    const float* bhh1 = (const float*)d_in[4];
    const float* Wih2 = (const float*)d_in[5];
    const float* Whh2 = (const float*)d_in[6];
    const float* bih2 = (const float*)d_in[7];
    const float* bhh2 = (const float*)d_in[8];
    const float* Wlin = (const float*)d_in[9];
    const float* blin = (const float*)d_in[10];
    float* out = (float*)d_out;

    const size_t h_bytes    = (size_t)4 * HB2 * sizeof(unsigned short);     // 1 MiB
    const size_t flag_bytes = (size_t)Cn * SLC * 64 * sizeof(unsigned);     // 64 KiB
    const size_t part_bytes = (size_t)Tn * Cn * SLC * Bn * sizeof(float);   // 16 MiB
    const int use_part = (ws_size >= h_bytes + flag_bytes + part_bytes) ? 1 : 0;

    hipMemsetAsync(d_ws, 0, h_bytes + flag_bytes, stream);   // zero h state + flags
    if (!use_part)
        hipMemsetAsync(d_out, 0, (size_t)out_size * sizeof(float), stream);

    lstm_mfma<<<NBLK, NTHR, 0, stream>>>(
        x, Wih1, Whh1, bih1, bhh1, Wih2, Whh2, bih2, bhh2, Wlin, blin, out, d_ws, use_part);

    if (use_part) {
        const float* part = (const float*)((const char*)d_ws + h_bytes + flag_bytes);
        reduce_out<<<Tn, Cn * Bn, 0, stream>>>(part, blin, out);
    }
}

// Round 7
// 4854.936 us; speedup vs baseline: 1.6566x; 1.6566x over previous
//
#include <hip/hip_runtime.h>

#define Bn 32
#define Tn 512
#define Cn 8
#define Hn 256
#define Gn 1024           // 4*Hn
#define NTHR 256          // 4 waves: 2 K-groups x 2 batch-groups
#define SLC  32           // slices per channel (each owns 8 h-indices, 32 gate rows)
#define NBLK (Cn*SLC)     // 256 workgroups
#define HP   (Hn/2)       // 128 packed uints per (b) per layer snapshot
#define CBP  (Cn*Bn*HP)   // 32768 uints per snapshot
#define PB2  (2*CBP)      // double-buffered packed-h array (uints)
#define GP   36           // gate-buffer pitch: 2-way banks on write & read (free)

typedef __attribute__((ext_vector_type(8))) __bf16 bf16x8;
typedef __attribute__((ext_vector_type(8))) short  short8;
typedef __attribute__((ext_vector_type(4))) float  f32x4;
typedef __attribute__((ext_vector_type(4))) unsigned uintx4;

__device__ __forceinline__ unsigned bfr(float f) {            // fp32 -> bf16 bits, RNE
    unsigned u = __float_as_uint(f);
    return (u + 0x7fffu + ((u >> 16) & 1u)) >> 16;
}
__device__ __forceinline__ float sigmf(float v)  { return 1.0f / (1.0f + __expf(-v)); }
__device__ __forceinline__ float tanh_f(float v) { return 1.0f - 2.0f / (__expf(2.0f * v) + 1.0f); }

__device__ __forceinline__ f32x4 mf(short8 a, short8 b, f32x4 c) {
    return __builtin_amdgcn_mfma_f32_16x16x32_bf16(
        __builtin_bit_cast(bf16x8, a), __builtin_bit_cast(bf16x8, b), c, 0, 0, 0);
}

// split 8 consecutive fp32 into bf16 hi + bf16 lo fragments
__device__ __forceinline__ void splitw(const float* __restrict__ p, short8& hi, short8& lo) {
    short8 h, l;
#pragma unroll
    for (int j = 0; j < 8; ++j) {
        const float v = p[j];
        const unsigned hb = bfr(v);
        h[j] = (short)hb;
        l[j] = (short)bfr(v - __uint_as_float(hb << 16));
    }
    hi = h; lo = l;
}

// coherence-point (agent-scope, cache-bypassing) dword ops — all compiler-generated
__device__ __forceinline__ void ast(unsigned* p, unsigned v) {
    __hip_atomic_store(p, v, __ATOMIC_RELAXED, __HIP_MEMORY_SCOPE_AGENT);
}
__device__ __forceinline__ unsigned ald(const unsigned* p) {
    return __hip_atomic_load(p, __ATOMIC_RELAXED, __HIP_MEMORY_SCOPE_AGENT);
}
// load a short8 (8 bf16) as 4 agent-scope dwords (pre-packed pairs, no unpack needed)
__device__ __forceinline__ short8 ald8(const unsigned* p) {
    uintx4 v;
    v.x = ald(p + 0); v.y = ald(p + 1); v.z = ald(p + 2); v.w = ald(p + 3);
    return __builtin_bit_cast(short8, v);
}

__global__ void __launch_bounds__(NTHR, 1)
lstm_mfma(const float* __restrict__ x,
          const float* __restrict__ Wih1, const float* __restrict__ Whh1,
          const float* __restrict__ bih1, const float* __restrict__ bhh1,
          const float* __restrict__ Wih2, const float* __restrict__ Whh2,
          const float* __restrict__ bih2, const float* __restrict__ bhh2,
          const float* __restrict__ Wlin, const float* __restrict__ blin,
          float* __restrict__ out, void* __restrict__ wsv, int use_part) {
    __shared__ float g1buf[2 * 32 * GP];   // [kg][32 gate rows][32 b] layer-1 K-partials
    __shared__ float g2buf[2 * 32 * GP];   // layer-2 K-partials

    unsigned* H1h = (unsigned*)wsv;        // [2][C][B][H/2] packed hi-pairs of h1
    unsigned* H1l = H1h + PB2;             // packed lo-pairs
    unsigned* H2h = H1l + PB2;
    unsigned* H2l = H2h + PB2;
    unsigned* flags = H2l + PB2;           // [C][SLC] monotone flags, 256B apart
    float* part = (float*)(flags + Cn * SLC * 64);  // [T][C][SLC][B] out partials

    const int tid  = threadIdx.x;
    const int wg   = blockIdx.x;
    const int c    = wg & 7;               // channel
    const int s    = wg >> 3;              // slice: h-indices s*8 .. s*8+7
    const int lane = tid & 63;
    const int wid  = tid >> 6;             // 0..3
    const int n    = lane & 15;
    const int quad = lane >> 4;
    const int kg   = wid & 1;              // K-group: k in [kg*128, kg*128+128)
    const int bbase = (wid >> 1) * 16;     // batch half

    // ---- permanent A-fragments: 3 weight matrices, 2 M-tiles, bf16 hi+lo, in VGPRs ----
    short8 w1h[2][4], w1l[2][4], w2h[2][4], w2l[2][4], w3h[2][4], w3l[2][4];
#pragma unroll
    for (int mt = 0; mt < 2; ++mt) {
        const int r = mt * 16 + n;                            // wg row (0..31)
        const size_t g = (size_t)((r >> 3) * Hn + s * 8 + (r & 7));
        const size_t base = (size_t)c * Gn * Hn + g * Hn + kg * 128 + quad * 8;
#pragma unroll
        for (int kk = 0; kk < 4; ++kk) {
            splitw(Whh1 + base + kk * 32, w1h[mt][kk], w1l[mt][kk]);
            splitw(Wih2 + base + kk * 32, w2h[mt][kk], w2l[mt][kk]);
            splitw(Whh2 + base + kk * 32, w3h[mt][kk], w3l[mt][kk]);
        }
    }

    // epilogue constants for the 8 accumulator rows (row = mt*16 + quad*4 + reg)
    float wi1_r[2][4], bs1_r[2][4], bs2_r[2][4];
#pragma unroll
    for (int mt = 0; mt < 2; ++mt)
#pragma unroll
        for (int reg = 0; reg < 4; ++reg) {
            const int r = mt * 16 + quad * 4 + reg;
            const int g = (r >> 3) * Hn + s * 8 + (r & 7);
            wi1_r[mt][reg] = Wih1[c * Gn + g];
            bs1_r[mt][reg] = bih1[c * Gn + g] + bhh1[c * Gn + g];
            bs2_r[mt][reg] = bih2[c * Gn + g] + bhh2[c * Gn + g];
        }

    // cell-update mapping: thread -> (jj = tid&7 h-idx within slice, bb = tid>>3 batch)
    const int jj = tid & 7;
    const int bb = tid >> 3;
    const float wl = Wlin[c * Hn + s * 8 + jj];
    const float bl = blin[c];

    float c1 = 0.0f, c2 = 0.0f;

    for (int t = 0; t <= Tn; ++t) {
        const bool doA = (t < Tn);      // layer-1 step t
        const bool doB = (t >= 1);      // layer-2 step t-1 (pipelined one behind)
        const int rd1 = (t + 1) & 1, wr1 = t & 1;        // h1 buffers
        const int rd2 = t & 1,       wr2 = (t + 1) & 1;  // h2 buffers

        const float xv = doA ? x[((bbase + n) * Tn + t) * Cn + c] : 0.0f;

        // ---- B-fragments via coherence-point loads (pre-packed hi/lo pairs) ----
        const int hb2 = ((rd2 * Cn + c) * Bn + (bbase + n)) * HP + kg * 64 + quad * 4;
        const int hb1 = ((rd1 * Cn + c) * Bn + (bbase + n)) * HP + kg * 64 + quad * 4;
        short8 f2h[4], f2l[4], f1h[4], f1l[4];
#pragma unroll
        for (int kk = 0; kk < 4; ++kk) {
            f2h[kk] = ald8(H2h + hb2 + kk * 16);
            f2l[kk] = ald8(H2l + hb2 + kk * 16);
            f1h[kk] = ald8(H1h + hb1 + kk * 16);
            f1l[kk] = ald8(H1l + hb1 + kk * 16);
        }

        f32x4 a1a[2] = {{0,0,0,0},{0,0,0,0}}, a1x[2] = {{0,0,0,0},{0,0,0,0}};
        f32x4 a2a[2] = {{0,0,0,0},{0,0,0,0}}, a2x[2] = {{0,0,0,0},{0,0,0,0}};
#pragma unroll
        for (int kk = 0; kk < 4; ++kk)
#pragma unroll
            for (int mt = 0; mt < 2; ++mt) {
                a2a[mt] = mf(w3h[mt][kk], f2h[kk], a2a[mt]);                       // Whh2.h2
                a2x[mt] = mf(w3l[mt][kk], f2h[kk], mf(w3h[mt][kk], f2l[kk], a2x[mt]));
                a1a[mt] = mf(w1h[mt][kk], f1h[kk], a1a[mt]);                       // Whh1.h1
                a1x[mt] = mf(w1l[mt][kk], f1h[kk], mf(w1h[mt][kk], f1l[kk], a1x[mt]));
                a2a[mt] = mf(w2h[mt][kk], f1h[kk], a2a[mt]);                       // Wih2.h1
                a2x[mt] = mf(w2l[mt][kk], f1h[kk], mf(w2h[mt][kk], f1l[kk], a2x[mt]));
            }

        // ---- write K-partial gates to LDS (C/D layout: col=lane&15, row=quad*4+reg) ----
#pragma unroll
        for (int mt = 0; mt < 2; ++mt)
#pragma unroll
            for (int reg = 0; reg < 4; ++reg) {
                const int r = mt * 16 + quad * 4 + reg;
                const int off = (kg * 32 + r) * GP + bbase + n;
                float e1 = a1a[mt][reg] + a1x[mt][reg];
                float e2 = a2a[mt][reg] + a2x[mt][reg];
                if (kg == 0) {                       // bias/x terms added once
                    e1 += xv * wi1_r[mt][reg] + bs1_r[mt][reg];
                    e2 += bs2_r[mt][reg];
                }
                g1buf[off] = e1;
                g2buf[off] = e2;
            }
        __syncthreads();

        // ---- layer-1 cell update, publish h1[t] as packed split-bf16 pairs ----
        if (doA) {
            const float iv = sigmf (g1buf[jj * GP + bb]        + g1buf[(32 + jj) * GP + bb]);
            const float fv = sigmf (g1buf[(8 + jj) * GP + bb]  + g1buf[(40 + jj) * GP + bb]);
            const float gv = tanh_f(g1buf[(16 + jj) * GP + bb] + g1buf[(48 + jj) * GP + bb]);
            const float ov = sigmf (g1buf[(24 + jj) * GP + bb] + g1buf[(56 + jj) * GP + bb]);
            c1 = fv * c1 + iv * gv;
            const float h1v = ov * tanh_f(c1);
            const unsigned hb = bfr(h1v);
            const unsigned lb = bfr(h1v - __uint_as_float(hb << 16));
            const unsigned packed = (hb << 16) | lb;
            const unsigned nbp = (unsigned)__shfl_xor((int)packed, 1, 64);
            if ((jj & 1) == 0) {
                const int pidx = ((wr1 * Cn + c) * Bn + bb) * HP + s * 4 + (jj >> 1);
                ast(&H1h[pidx], (packed >> 16) | (nbp & 0xffff0000u));
                ast(&H1l[pidx], (packed & 0xffffu) | (nbp << 16));
            }
        }
        // ---- layer-2 cell update, publish h2[t-1], out partial ----
        if (doB) {
            const float iv = sigmf (g2buf[jj * GP + bb]        + g2buf[(32 + jj) * GP + bb]);
            const float fv = sigmf (g2buf[(8 + jj) * GP + bb]  + g2buf[(40 + jj) * GP + bb]);
            const float gv = tanh_f(g2buf[(16 + jj) * GP + bb] + g2buf[(48 + jj) * GP + bb]);
            const float ov = sigmf (g2buf[(24 + jj) * GP + bb] + g2buf[(56 + jj) * GP + bb]);
            c2 = fv * c2 + iv * gv;
            const float h2v = ov * tanh_f(c2);
            const unsigned hb = bfr(h2v);
            const unsigned lb = bfr(h2v - __uint_as_float(hb << 16));
            const unsigned packed = (hb << 16) | lb;
            const unsigned nbp = (unsigned)__shfl_xor((int)packed, 1, 64);
            if ((jj & 1) == 0) {
                const int pidx = ((wr2 * Cn + c) * Bn + bb) * HP + s * 4 + (jj >> 1);
                ast(&H2h[pidx], (packed >> 16) | (nbp & 0xffff0000u));
                ast(&H2l[pidx], (packed & 0xffffu) | (nbp << 16));
            }

            float pv = h2v * wl;                      // partial of out over this slice's 8 h
            pv += __shfl_xor(pv, 1, 64);
            pv += __shfl_xor(pv, 2, 64);
            pv += __shfl_xor(pv, 4, 64);
            if (jj == 0) {
                if (use_part) {
                    part[(((t - 1) * Cn + c) * SLC + s) * Bn + bb] = pv;
                } else {
                    atomicAdd(&out[(bb * Tn + (t - 1)) * Cn + c], pv + (s == 0 ? bl : 0.0f));
                }
            }
        }

        // ---- fence-free channel barrier: syncthreads drains the write-through h stores,
        //      then monotone flag handshake via agent-scope atomics (r4-proven primitive) ----
        __syncthreads();
        if (tid == 0)
            ast(&flags[(c * SLC + s) * 64], (unsigned)(t + 1));
        if (tid < 64) {
            bool mine;
            do {
                mine = (tid >= SLC) ||
                       (ald(&flags[(c * SLC + tid) * 64]) >= (unsigned)(t + 1));
                if (__all((int)mine)) break;
                __builtin_amdgcn_s_sleep(1);
            } while (true);
        }
        __syncthreads();
    }
}

__global__ void reduce_out(const float* __restrict__ part, const float* __restrict__ blin,
                           float* __restrict__ out) {
    const int t = blockIdx.x;           // 512
    const int c = threadIdx.x >> 5;     // 8
    const int b = threadIdx.x & 31;     // 32
    float v = blin[c];
#pragma unroll
    for (int s = 0; s < SLC; ++s) v += part[((t * Cn + c) * SLC + s) * Bn + b];
    out[(b * Tn + t) * Cn + c] = v;
}

extern "C" void kernel_launch(void* const* d_in, const int* in_sizes, int n_in,
                              void* d_out, int out_size, void* d_ws, size_t ws_size,
                              hipStream_t stream) {
    const float* x    = (const float*)d_in[0];
    const float* Wih1 = (const float*)d_in[1];
    const float* Whh1 = (const float*)d_in[2];
    const float* bih1 = (const float*)d_in[3];
    const float* bhh1 = (const float*)d_in[4];
    const float* Wih2 = (const float*)d_in[5];
    const float* Whh2 = (const float*)d_in[6];
    const float* bih2 = (const float*)d_in[7];
    const float* bhh2 = (const float*)d_in[8];
    const float* Wlin = (const float*)d_in[9];
    const float* blin = (const float*)d_in[10];
    float* out = (float*)d_out;

    const size_t h_bytes    = (size_t)4 * PB2 * sizeof(unsigned);           // 1 MiB
    const size_t flag_bytes = (size_t)Cn * SLC * 64 * sizeof(unsigned);     // 64 KiB
    const size_t part_bytes = (size_t)Tn * Cn * SLC * Bn * sizeof(float);   // 16 MiB
    const int use_part = (ws_size >= h_bytes + flag_bytes + part_bytes) ? 1 : 0;

    hipMemsetAsync(d_ws, 0, h_bytes + flag_bytes, stream);   // zero h state + flags
    if (!use_part)
        hipMemsetAsync(d_out, 0, (size_t)out_size * sizeof(float), stream);

    lstm_mfma<<<NBLK, NTHR, 0, stream>>>(
        x, Wih1, Whh1, bih1, bhh1, Wih2, Whh2, bih2, bhh2, Wlin, blin, out, d_ws, use_part);

    if (use_part) {
        const float* part = (const float*)((const char*)d_ws + h_bytes + flag_bytes);
        reduce_out<<<Tn, Cn * Bn, 0, stream>>>(part, blin, out);
    }
}

// Round 8
// 2732.558 us; speedup vs baseline: 2.9432x; 1.7767x over previous
//
#include <hip/hip_runtime.h>

#define Bn 32
#define Tn 512
#define Cn 8
#define Hn 256
#define Gn 1024           // 4*Hn
#define NTHR 256          // 4 waves: 2 K-groups x 2 batch-groups
#define SLC  32           // slices per channel (each owns 8 h-indices, 32 gate rows)
#define NBLK (Cn*SLC)     // 256 workgroups
#define K2n  (Hn/2)       // 128 k-pairs
#define EXU  (2*Cn*K2n*Bn) // 8-byte units per layer exchange array (double-buffered)
#define GP   36           // gate-buffer pitch: 2-way banks on write & read (free)

typedef __attribute__((ext_vector_type(8))) __bf16 bf16x8;
typedef __attribute__((ext_vector_type(8))) short  short8;
typedef __attribute__((ext_vector_type(4))) float  f32x4;
typedef __attribute__((ext_vector_type(4))) unsigned uintx4;
typedef unsigned long long u64;

__device__ __forceinline__ unsigned bfr(float f) {            // fp32 -> bf16 bits, RNE
    unsigned u = __float_as_uint(f);
    return (u + 0x7fffu + ((u >> 16) & 1u)) >> 16;
}
__device__ __forceinline__ float sigmf(float v)  { return 1.0f / (1.0f + __expf(-v)); }
__device__ __forceinline__ float tanh_f(float v) { return 1.0f - 2.0f / (__expf(2.0f * v) + 1.0f); }

__device__ __forceinline__ f32x4 mf(short8 a, short8 b, f32x4 c) {
    return __builtin_amdgcn_mfma_f32_16x16x32_bf16(
        __builtin_bit_cast(bf16x8, a), __builtin_bit_cast(bf16x8, b), c, 0, 0, 0);
}

// split 8 consecutive fp32 into bf16 hi + bf16 lo fragments
__device__ __forceinline__ void splitw(const float* __restrict__ p, short8& hi, short8& lo) {
    short8 h, l;
#pragma unroll
    for (int j = 0; j < 8; ++j) {
        const float v = p[j];
        const unsigned hb = bfr(v);
        h[j] = (short)hb;
        l[j] = (short)bfr(v - __uint_as_float(hb << 16));
    }
    hi = h; lo = l;
}

// coherence-point (agent-scope, cache-bypassing) ops — all compiler-generated
__device__ __forceinline__ void ast(unsigned* p, unsigned v) {
    __hip_atomic_store(p, v, __ATOMIC_RELAXED, __HIP_MEMORY_SCOPE_AGENT);
}
__device__ __forceinline__ unsigned ald(const unsigned* p) {
    return __hip_atomic_load(p, __ATOMIC_RELAXED, __HIP_MEMORY_SCOPE_AGENT);
}
__device__ __forceinline__ void ast64(u64* p, u64 v) {
    __hip_atomic_store(p, v, __ATOMIC_RELAXED, __HIP_MEMORY_SCOPE_AGENT);
}
__device__ __forceinline__ u64 ald64(const u64* p) {
    return __hip_atomic_load(p, __ATOMIC_RELAXED, __HIP_MEMORY_SCOPE_AGENT);
}

__global__ void __launch_bounds__(NTHR, 1)
lstm_mfma(const float* __restrict__ x,
          const float* __restrict__ Wih1, const float* __restrict__ Whh1,
          const float* __restrict__ bih1, const float* __restrict__ bhh1,
          const float* __restrict__ Wih2, const float* __restrict__ Whh2,
          const float* __restrict__ bih2, const float* __restrict__ bhh2,
          const float* __restrict__ Wlin, const float* __restrict__ blin,
          float* __restrict__ out, void* __restrict__ wsv, int use_part) {
    __shared__ float g1buf[2 * 32 * GP];   // [kg][32 gate rows][32 b] layer-1 K-partials
    __shared__ float g2buf[2 * 32 * GP];   // layer-2 K-partials

    // exchange arrays: [2 buf][C][K2=128][B=32] of (hi-pair dword, lo-pair dword)
    u64* EX1 = (u64*)wsv;
    u64* EX2 = EX1 + EXU;
    unsigned* flags = (unsigned*)(EX2 + EXU);       // [C][SLC] monotone flags, 256B apart
    float* part = (float*)(flags + Cn * SLC * 64);  // [T][C][SLC][B] out partials

    const int tid  = threadIdx.x;
    const int wg   = blockIdx.x;
    const int c    = wg & 7;               // channel
    const int s    = wg >> 3;              // slice: h-indices s*8 .. s*8+7
    const int lane = tid & 63;
    const int wid  = tid >> 6;             // 0..3
    const int n    = lane & 15;
    const int quad = lane >> 4;
    const int kg   = wid & 1;              // K-group: k in [kg*128, kg*128+128)
    const int bbase = (wid >> 1) * 16;     // batch half
    const int bn = bbase + n;

    // ---- permanent A-fragments: 3 weight matrices, 2 M-tiles, bf16 hi+lo, in VGPRs ----
    short8 w1h[2][4], w1l[2][4], w2h[2][4], w2l[2][4], w3h[2][4], w3l[2][4];
#pragma unroll
    for (int mt = 0; mt < 2; ++mt) {
        const int r = mt * 16 + n;                            // wg row (0..31)
        const size_t g = (size_t)((r >> 3) * Hn + s * 8 + (r & 7));
        const size_t base = (size_t)c * Gn * Hn + g * Hn + kg * 128 + quad * 8;
#pragma unroll
        for (int kk = 0; kk < 4; ++kk) {
            splitw(Whh1 + base + kk * 32, w1h[mt][kk], w1l[mt][kk]);
            splitw(Wih2 + base + kk * 32, w2h[mt][kk], w2l[mt][kk]);
            splitw(Whh2 + base + kk * 32, w3h[mt][kk], w3l[mt][kk]);
        }
    }

    // epilogue constants for the 8 accumulator rows (row = mt*16 + quad*4 + reg)
    float wi1_r[2][4], bs1_r[2][4], bs2_r[2][4];
#pragma unroll
    for (int mt = 0; mt < 2; ++mt)
#pragma unroll
        for (int reg = 0; reg < 4; ++reg) {
            const int r = mt * 16 + quad * 4 + reg;
            const int g = (r >> 3) * Hn + s * 8 + (r & 7);
            wi1_r[mt][reg] = Wih1[c * Gn + g];
            bs1_r[mt][reg] = bih1[c * Gn + g] + bhh1[c * Gn + g];
            bs2_r[mt][reg] = bih2[c * Gn + g] + bhh2[c * Gn + g];
        }

    // cell-update mapping: thread -> (jj = tid&7 h-idx within slice, bb = tid>>3 batch)
    const int jj = tid & 7;
    const int bb = tid >> 3;
    const float wl = Wlin[c * Hn + s * 8 + jj];
    const float bl = blin[c];

    float c1 = 0.0f, c2 = 0.0f;

    for (int t = 0; t <= Tn; ++t) {
        const bool doA = (t < Tn);      // layer-1 step t
        const bool doB = (t >= 1);      // layer-2 step t-1 (pipelined one behind)
        const int rd1 = (t + 1) & 1, wr1 = t & 1;        // h1 buffers
        const int rd2 = t & 1,       wr2 = (t + 1) & 1;  // h2 buffers

        const float xv = doA ? x[(bn * Tn + t) * Cn + c] : 0.0f;

        // ---- B-fragments via 8-byte coherence-point loads, [k2][b] layout:
        //      lane-n contiguous (128 B / 16 lanes), every 64 B sector fully used ----
        const u64* E1 = EX1 + (size_t)(rd1 * Cn + c) * K2n * Bn;
        const u64* E2 = EX2 + (size_t)(rd2 * Cn + c) * K2n * Bn;
        short8 f2h[4], f2l[4], f1h[4], f1l[4];
#pragma unroll
        for (int kk = 0; kk < 4; ++kk) {
            uintx4 a2h, a2l, a1h, a1l;
#pragma unroll
            for (int j2 = 0; j2 < 4; ++j2) {
                const int k2 = kg * 64 + kk * 16 + quad * 4 + j2;
                const u64 v2 = ald64(E2 + k2 * Bn + bn);
                const u64 v1 = ald64(E1 + k2 * Bn + bn);
                a2h[j2] = (unsigned)v2; a2l[j2] = (unsigned)(v2 >> 32);
                a1h[j2] = (unsigned)v1; a1l[j2] = (unsigned)(v1 >> 32);
            }
            f2h[kk] = __builtin_bit_cast(short8, a2h);
            f2l[kk] = __builtin_bit_cast(short8, a2l);
            f1h[kk] = __builtin_bit_cast(short8, a1h);
            f1l[kk] = __builtin_bit_cast(short8, a1l);
        }

        f32x4 a1a[2] = {{0,0,0,0},{0,0,0,0}}, a1x[2] = {{0,0,0,0},{0,0,0,0}};
        f32x4 a2a[2] = {{0,0,0,0},{0,0,0,0}}, a2x[2] = {{0,0,0,0},{0,0,0,0}};
#pragma unroll
        for (int kk = 0; kk < 4; ++kk)
#pragma unroll
            for (int mt = 0; mt < 2; ++mt) {
                a2a[mt] = mf(w3h[mt][kk], f2h[kk], a2a[mt]);                       // Whh2.h2
                a2x[mt] = mf(w3l[mt][kk], f2h[kk], mf(w3h[mt][kk], f2l[kk], a2x[mt]));
                a1a[mt] = mf(w1h[mt][kk], f1h[kk], a1a[mt]);                       // Whh1.h1
                a1x[mt] = mf(w1l[mt][kk], f1h[kk], mf(w1h[mt][kk], f1l[kk], a1x[mt]));
                a2a[mt] = mf(w2h[mt][kk], f1h[kk], a2a[mt]);                       // Wih2.h1
                a2x[mt] = mf(w2l[mt][kk], f1h[kk], mf(w2h[mt][kk], f1l[kk], a2x[mt]));
            }

        // ---- write K-partial gates to LDS (C/D layout: col=lane&15, row=quad*4+reg) ----
#pragma unroll
        for (int mt = 0; mt < 2; ++mt)
#pragma unroll
            for (int reg = 0; reg < 4; ++reg) {
                const int r = mt * 16 + quad * 4 + reg;
                const int off = (kg * 32 + r) * GP + bbase + n;
                float e1 = a1a[mt][reg] + a1x[mt][reg];
                float e2 = a2a[mt][reg] + a2x[mt][reg];
                if (kg == 0) {                       // bias/x terms added once
                    e1 += xv * wi1_r[mt][reg] + bs1_r[mt][reg];
                    e2 += bs2_r[mt][reg];
                }
                g1buf[off] = e1;
                g2buf[off] = e2;
            }
        __syncthreads();

        // ---- layer-1 cell update, publish h1[t] as packed (hi,lo) 8-byte stores ----
        if (doA) {
            const float iv = sigmf (g1buf[jj * GP + bb]        + g1buf[(32 + jj) * GP + bb]);
            const float fv = sigmf (g1buf[(8 + jj) * GP + bb]  + g1buf[(40 + jj) * GP + bb]);
            const float gv = tanh_f(g1buf[(16 + jj) * GP + bb] + g1buf[(48 + jj) * GP + bb]);
            const float ov = sigmf (g1buf[(24 + jj) * GP + bb] + g1buf[(56 + jj) * GP + bb]);
            c1 = fv * c1 + iv * gv;
            const float h1v = ov * tanh_f(c1);
            const unsigned hb = bfr(h1v);
            const unsigned lb = bfr(h1v - __uint_as_float(hb << 16));
            const unsigned packed = (hb << 16) | lb;
            const unsigned nbp = (unsigned)__shfl_xor((int)packed, 1, 64);
            if ((jj & 1) == 0) {
                const unsigned hip = (packed >> 16) | (nbp & 0xffff0000u);   // even k lo-half
                const unsigned lop = (packed & 0xffffu) | (nbp << 16);
                const int k2 = s * 4 + (jj >> 1);
                ast64(EX1 + (size_t)(wr1 * Cn + c) * K2n * Bn + k2 * Bn + bb,
                      (u64)hip | ((u64)lop << 32));
            }
        }
        // ---- layer-2 cell update, publish h2[t-1], out partial ----
        if (doB) {
            const float iv = sigmf (g2buf[jj * GP + bb]        + g2buf[(32 + jj) * GP + bb]);
            const float fv = sigmf (g2buf[(8 + jj) * GP + bb]  + g2buf[(40 + jj) * GP + bb]);
            const float gv = tanh_f(g2buf[(16 + jj) * GP + bb] + g2buf[(48 + jj) * GP + bb]);
            const float ov = sigmf (g2buf[(24 + jj) * GP + bb] + g2buf[(56 + jj) * GP + bb]);
            c2 = fv * c2 + iv * gv;
            const float h2v = ov * tanh_f(c2);
            const unsigned hb = bfr(h2v);
            const unsigned lb = bfr(h2v - __uint_as_float(hb << 16));
            const unsigned packed = (hb << 16) | lb;
            const unsigned nbp = (unsigned)__shfl_xor((int)packed, 1, 64);
            if ((jj & 1) == 0) {
                const unsigned hip = (packed >> 16) | (nbp & 0xffff0000u);
                const unsigned lop = (packed & 0xffffu) | (nbp << 16);
                const int k2 = s * 4 + (jj >> 1);
                ast64(EX2 + (size_t)(wr2 * Cn + c) * K2n * Bn + k2 * Bn + bb,
                      (u64)hip | ((u64)lop << 32));
            }

            float pv = h2v * wl;                      // partial of out over this slice's 8 h
            pv += __shfl_xor(pv, 1, 64);
            pv += __shfl_xor(pv, 2, 64);
            pv += __shfl_xor(pv, 4, 64);
            if (jj == 0) {
                if (use_part) {
                    part[(((t - 1) * Cn + c) * SLC + s) * Bn + bb] = pv;
                } else {
                    atomicAdd(&out[(bb * Tn + (t - 1)) * Cn + c], pv + (s == 0 ? bl : 0.0f));
                }
            }
        }

        // ---- fence-free channel barrier (r7-proven): syncthreads drains the
        //      write-through h stores, then monotone flag handshake ----
        __syncthreads();
        if (tid == 0)
            ast(&flags[(c * SLC + s) * 64], (unsigned)(t + 1));
        if (tid < 64) {
            bool mine;
            do {
                mine = (tid >= SLC) ||
                       (ald(&flags[(c * SLC + tid) * 64]) >= (unsigned)(t + 1));
                if (__all((int)mine)) break;
                __builtin_amdgcn_s_sleep(1);
            } while (true);
        }
        __syncthreads();
    }
}

__global__ void reduce_out(const float* __restrict__ part, const float* __restrict__ blin,
                           float* __restrict__ out) {
    const int t = blockIdx.x;           // 512
    const int c = threadIdx.x >> 5;     // 8
    const int b = threadIdx.x & 31;     // 32
    float v = blin[c];
#pragma unroll
    for (int s = 0; s < SLC; ++s) v += part[((t * Cn + c) * SLC + s) * Bn + b];
    out[(b * Tn + t) * Cn + c] = v;
}

extern "C" void kernel_launch(void* const* d_in, const int* in_sizes, int n_in,
                              void* d_out, int out_size, void* d_ws, size_t ws_size,
                              hipStream_t stream) {
    const float* x    = (const float*)d_in[0];
    const float* Wih1 = (const float*)d_in[1];
    const float* Whh1 = (const float*)d_in[2];
    const float* bih1 = (const float*)d_in[3];
    const float* bhh1 = (const float*)d_in[4];
    const float* Wih2 = (const float*)d_in[5];
    const float* Whh2 = (const float*)d_in[6];
    const float* bih2 = (const float*)d_in[7];
    const float* bhh2 = (const float*)d_in[8];
    const float* Wlin = (const float*)d_in[9];
    const float* blin = (const float*)d_in[10];
    float* out = (float*)d_out;

    const size_t h_bytes    = (size_t)2 * EXU * sizeof(u64);                // 1 MiB
    const size_t flag_bytes = (size_t)Cn * SLC * 64 * sizeof(unsigned);     // 64 KiB
    const size_t part_bytes = (size_t)Tn * Cn * SLC * Bn * sizeof(float);   // 16 MiB
    const int use_part = (ws_size >= h_bytes + flag_bytes + part_bytes) ? 1 : 0;

    hipMemsetAsync(d_ws, 0, h_bytes + flag_bytes, stream);   // zero h state + flags
    if (!use_part)
        hipMemsetAsync(d_out, 0, (size_t)out_size * sizeof(float), stream);

    lstm_mfma<<<NBLK, NTHR, 0, stream>>>(
        x, Wih1, Whh1, bih1, bhh1, Wih2, Whh2, bih2, bhh2, Wlin, blin, out, d_ws, use_part);

    if (use_part) {
        const float* part = (const float*)((const char*)d_ws + h_bytes + flag_bytes);
        reduce_out<<<Tn, Cn * Bn, 0, stream>>>(part, blin, out);
    }
}